// Round 8
// baseline (677.246 us; speedup 1.0000x reference)
//
#include <hip/hip_runtime.h>
#include <math.h>

#define B_ 256
#define S_ 512
#define K_ 20
#define D_ 256
#define NT 512
#define LDH 264   // LDS row stride (shorts), 16B-aligned rows, bank-spread

typedef __attribute__((ext_vector_type(8))) short short8;
typedef __attribute__((ext_vector_type(4))) float f32x4;
typedef __attribute__((ext_vector_type(8))) _Float16 half8;
typedef __attribute__((ext_vector_type(2))) __fp16 fp16x2;   // cvt_pkrtz result type
typedef __attribute__((ext_vector_type(2))) unsigned int uint2v;

__device__ __forceinline__ unsigned short rne_bf16(float f) {
  unsigned u = __builtin_bit_cast(unsigned, f);
  u += 0x7FFFu + ((u >> 16) & 1u);
  return (unsigned short)(u >> 16);
}
__device__ __forceinline__ float bf16_to_f32(unsigned short h) {
  return __builtin_bit_cast(float, ((unsigned)h) << 16);
}
__device__ __forceinline__ unsigned pk_f16(float a, float b) {
  fp16x2 p = __builtin_amdgcn_cvt_pkrtz(a, b);  // v_cvt_pkrtz_f16_f32
  return __builtin_bit_cast(unsigned, p);
}

// rnn_fused14: R6 (rnn_fused12) + phase-split MFMA (ke0 chains complete
// before ke1 start -> ke0 epilogue hides under ke1 MFMA shadow) + xk register
// prefetch. Scalar fmaf epilogue (R7's v_pk_* asm had wrong packed semantics
// -> reverted; phase-split itself is bitwise identical).
__global__ __launch_bounds__(NT, 2)
void rnn_fused14(const float* __restrict__ es, const int* __restrict__ mask,
                 const float* __restrict__ keys, const float* __restrict__ U,
                 const float* __restrict__ V, const float* __restrict__ W,
                 float* __restrict__ XWc, float* __restrict__ out) {
  __shared__ unsigned short sH0[32 * LDH];  // state buf 0 (prologue: hi staging)
  __shared__ unsigned short sH1[32 * LDH];  // state buf 1 (prologue: lo staging)
  __shared__ float sRed[2][2][32][13];      // [buf][psq/pxh][k-row][wave + pad]
  __shared__ float sXK[512 * 20 + 16];      // precomputed x_i . keys
  __shared__ short sAct[S_];
  __shared__ int   sNact;

  const int b = blockIdx.x, t = threadIdx.x;
  const int w = t >> 6, lane = t & 63, quad = lane >> 4, n = lane & 15;
  const int e0a = (w << 5) + quad * 4;

  // ---- P0: zero sRed (rows 20..31 stay 0 forever); compact active list ----
  for (int i = t; i < 2 * 2 * 32 * 13; i += NT) ((float*)sRed)[i] = 0.0f;
  if (w == 0) {
    int base = 0;
    for (int c = 0; c < 8; ++c) {
      int s = c * 64 + lane;
      int mv = mask[b * S_ + s];
      unsigned long long bal = __ballot(mv != 0);
      int pos = base + (int)__popcll(bal & ((1ull << lane) - 1ull));
      if (mv) sAct[pos] = (short)s;
      base += (int)__popcll(bal);
    }
    if (lane == 0) sNact = base;
  }
  __syncthreads();
  const int nAct = sNact;

  short8 aHi[8][2], aLo[8][2];  // split-bf16 A-frags (keys, then W, then V)
  auto load_A = [&](const float* __restrict__ M) {
#pragma unroll
    for (int kt = 0; kt < 8; ++kt)
#pragma unroll
      for (int et = 0; et < 2; ++et) {
        const int e = ((2 * w + et) << 4) + n;
        const int d0 = kt * 32 + quad * 8;
        short8 h8, l8;
#pragma unroll
        for (int j = 0; j < 8; ++j) {
          float f = M[(d0 + j) * D_ + e];
          unsigned short hi = rne_bf16(f);
          h8[j] = (short)hi;
          l8[j] = (short)rne_bf16(f - bf16_to_f32(hi));
        }
        aHi[kt][et] = h8; aLo[kt][et] = l8;
      }
  };
  // keys as A: A[row=k][d] = keys[k][d]; rows >= 20 (all waves > 0) are zero.
  auto load_A_keys = [&]() {
#pragma unroll
    for (int kt = 0; kt < 8; ++kt)
#pragma unroll
      for (int et = 0; et < 2; ++et) {
        const int kk2 = ((2 * w + et) << 4) + n;
        const int d0 = kt * 32 + quad * 8;
        short8 h8 = {}, l8 = {};
        if (kk2 < K_) {
#pragma unroll
          for (int j = 0; j < 8; ++j) {
            float f = keys[(size_t)(b * K_ + kk2) * D_ + d0 + j];
            unsigned short hi = rne_bf16(f);
            h8[j] = (short)hi;
            l8[j] = (short)rne_bf16(f - bf16_to_f32(hi));
          }
        }
        aHi[kt][et] = h8; aLo[kt][et] = l8;
      }
  };
  auto run_mfma3 = [&](f32x4 acc[2][2]) {  // split-bf16 3-product (hi sH0, lo sH1)
#pragma unroll
    for (int kt = 0; kt < 8; ++kt) {
      short8 bhi[2], blo[2];
#pragma unroll
      for (int ke = 0; ke < 2; ++ke) {
        const int off = (ke * 16 + n) * LDH + kt * 32 + quad * 8;
        bhi[ke] = *(const short8*)&sH0[off];
        blo[ke] = *(const short8*)&sH1[off];
      }
#pragma unroll
      for (int et = 0; et < 2; ++et)
#pragma unroll
        for (int ke = 0; ke < 2; ++ke) {
          acc[et][ke] = __builtin_amdgcn_mfma_f32_16x16x32_bf16(aHi[kt][et], bhi[ke], acc[et][ke], 0, 0, 0);
          acc[et][ke] = __builtin_amdgcn_mfma_f32_16x16x32_bf16(aLo[kt][et], bhi[ke], acc[et][ke], 0, 0, 0);
          acc[et][ke] = __builtin_amdgcn_mfma_f32_16x16x32_bf16(aHi[kt][et], blo[ke], acc[et][ke], 0, 0, 0);
        }
    }
  };
  // stage 32 gathered es rows (pass p), split-bf16
  auto stage_rows = [&](int p) {
    const int rr = t >> 4, c0 = (t & 15) * 16;
    const int ridx = p * 32 + rr;
    const int sidx = sAct[(ridx < nAct) ? ridx : (nAct - 1)];
    const float* src = es + ((size_t)b * S_ + sidx) * D_ + c0;
#pragma unroll
    for (int h2 = 0; h2 < 2; ++h2) {
      f32x4 f0 = *(const f32x4*)(src + h2 * 8);
      f32x4 f1 = *(const f32x4*)(src + h2 * 8 + 4);
      short8 hh, ll;
#pragma unroll
      for (int j = 0; j < 4; ++j) {
        unsigned short a = rne_bf16(f0[j]);
        hh[j] = (short)a; ll[j] = (short)rne_bf16(f0[j] - bf16_to_f32(a));
        unsigned short bq = rne_bf16(f1[j]);
        hh[4 + j] = (short)bq; ll[4 + j] = (short)rne_bf16(f1[j] - bf16_to_f32(bq));
      }
      *(short8*)&sH0[rr * LDH + c0 + h2 * 8] = hh;
      *(short8*)&sH1[rr * LDH + c0 + h2 * 8] = ll;
    }
  };

  const size_t bbase = (size_t)b * S_;
  const int nPass = (nAct + 31) >> 5;

  // ---- Phase XK: sXK[g][k] = es_act[g] . keys[k] (wave0-only MFMA) ----
  if (nAct > 0) {
    load_A_keys();
    for (int p = 0; p < nPass; ++p) {
      stage_rows(p);
      __syncthreads();
      if (w == 0) {
        f32x4 axk[2][2] = {};
        run_mfma3(axk);
#pragma unroll
        for (int et = 0; et < 2; ++et) {
          const int kb = et * 16 + quad * 4;
          if (kb < K_) {
#pragma unroll
            for (int ke = 0; ke < 2; ++ke) {
              const int row = p * 32 + ke * 16 + n;
              *(f32x4*)&sXK[row * 20 + kb] = axk[et][ke];
            }
          }
        }
      }
      __syncthreads();
    }
  }

  // ---- Phase XW: compact x@W for this batch's active rows -> scratch ----
  if (nAct > 0) {
    load_A(W);
    for (int p = 0; p < nPass; ++p) {
      stage_rows(p);
      __syncthreads();
      f32x4 acc[2][2] = {};
      run_mfma3(acc);
#pragma unroll
      for (int et = 0; et < 2; ++et)
#pragma unroll
        for (int ke = 0; ke < 2; ++ke) {
          const int g = p * 32 + ke * 16 + n;
          if (g < nAct)
            *(f32x4*)&XWc[(bbase + g) * D_ + e0a + 16 * et] = acc[et][ke];
        }
      __syncthreads();
    }
  }

  // ---- zero BOTH buffers fully (rows 20..31 + pads stay 0 afterwards) ----
  for (int i = t; i < 32 * LDH; i += NT) { sH0[i] = 0; sH1[i] = 0; }
  __syncthreads();

  // ---- keys staging (split-bf16) + V frags ----
  for (int i = t; i < K_ * D_; i += NT) {
    int k = i >> 8, d = i & 255;
    float f = keys[(b * K_ + k) * D_ + d];
    unsigned short hi = rne_bf16(f);
    sH0[k * LDH + d] = hi;
    sH1[k * LDH + d] = rne_bf16(f - bf16_to_f32(hi));
  }
  load_A(V);
  __syncthreads();

  f32x4 kvReg[2][2] = {};
  run_mfma3(kvReg);
  __syncthreads();  // kV reads done

  // ---- zero state rows (both buffers); load U as fp16 frags ----
  for (int i = t; i < K_ * LDH; i += NT) { sH0[i] = 0; sH1[i] = 0; }
  short8 aU[8][2];  // fp16 U^T frags (single product in the loop)
#pragma unroll
  for (int kt = 0; kt < 8; ++kt)
#pragma unroll
    for (int et = 0; et < 2; ++et) {
      const int e = ((2 * w + et) << 4) + n;
      const int d0 = kt * 32 + quad * 8;
      short8 h8;
#pragma unroll
      for (int j = 0; j < 8; ++j)
        h8[j] = (short)__builtin_bit_cast(unsigned short, (_Float16)U[(d0 + j) * D_ + e]);
      aU[kt][et] = h8;
    }

  f32x4 hReg[2][2] = {};
  f32x4 xEc[2] = {}, xwEc[2] = {};
  float xkC = 0.0f;
  const int kk = lane & 31;
  if (nAct > 0) {
    const int s1 = sAct[(nAct > 1) ? 1 : 0];
#pragma unroll
    for (int et = 0; et < 2; ++et) {
      xEc[et]  = *(const f32x4*)&es[((size_t)b * S_ + s1) * D_ + e0a + 16 * et];
      xwEc[et] = *(const f32x4*)&XWc[bbase * D_ + e0a + 16 * et];
    }
    xkC = sXK[kk];  // step-0 x.keys (rows >= 20: finite garbage, unused)
  }
  __syncthreads();  // ready for step 0 (sRed zeros = correct h0=0 seed)

  // cross-half swap on VALU pipe
  auto xswap = [](float& a, float& b) {
    asm("v_permlane32_swap_b32 %0, %1" : "+v"(a), "+v"(b));
  };

  // scalar epilogue for one (et,ke) tile; accumulates psq/pxh.
  auto epi_tile = [&](const f32x4& a4, const f32x4& kv4, const f32x4& xw4,
                      const f32x4& xn4, float lm, float g, f32x4& hR,
                      float& psq, float& pxh, unsigned short* wptr, bool doWrite) {
    f32x4 u;
#pragma unroll
    for (int r = 0; r < 4; ++r) {
      float T = fmaxf(fmaf(lm, a4[r], kv4[r] + xw4[r]), 0.0f);
      float uv = fmaf(g, T, lm * hR[r]);
      u[r] = uv;
      psq = fmaf(uv, uv, psq);
      pxh = fmaf(xn4[r], uv, pxh);
    }
    hR = u;
    uint2v hh;
    hh[0] = pk_f16(u[0], u[1]);
    hh[1] = pk_f16(u[2], u[3]);
    if (doWrite) *(uint2v*)wptr = hh;
  };

  // ---- recurrence: one barrier per step ----
  for (int i = 0; i < nAct; ++i) {
    const int rb = i & 1, wbuf = rb ^ 1;
    const unsigned short* bR = rb ? sH1 : sH0;
    unsigned short* bW = rb ? sH0 : sH1;

    // next-slot loads (consumed in epilogue of step i+1)
    const int iX = (i + 2 < nAct) ? i + 2 : nAct - 1;
    const int iW = (i + 1 < nAct) ? i + 1 : nAct - 1;
    const size_t rX = ((size_t)b * S_ + sAct[iX]) * D_;
    f32x4 xEn[2], xwEn[2];
#pragma unroll
    for (int et = 0; et < 2; ++et) {
      xEn[et]  = *(const f32x4*)&es[rX + e0a + 16 * et];
      xwEn[et] = *(const f32x4*)&XWc[(bbase + iW) * D_ + e0a + 16 * et];
    }
    const float xkN = sXK[iW * 20 + kk];  // prefetch next step's x.keys

    // single-stream per-lane lam/g: lane computes k = lane&31
    float lmv, gv;
    {
      f32x4 qa = *(const f32x4*)&sRed[rb][0][kk][0];
      f32x4 qb = *(const f32x4*)&sRed[rb][0][kk][4];
      f32x4 ha = *(const f32x4*)&sRed[rb][1][kk][0];
      f32x4 hb = *(const f32x4*)&sRed[rb][1][kk][4];
      f32x4 qs = qa + qb, hs = ha + hb;
      float ss = (qs[0] + qs[1]) + (qs[2] + qs[3]);
      float xh = (hs[0] + hs[1]) + (hs[2] + hs[3]);
      lmv = rsqrtf(fmaxf(ss, 1e-12f));
      gv = __fdividef(1.0f, 1.0f + __expf(-fmaf(lmv, xh, xkC)));
    }
    const float lm0 = __builtin_bit_cast(float, __builtin_amdgcn_ds_swizzle(__builtin_bit_cast(int, lmv), 0x000F));
    const float g0  = __builtin_bit_cast(float, __builtin_amdgcn_ds_swizzle(__builtin_bit_cast(int, gv),  0x000F));
    const float lm1s = __builtin_bit_cast(float, __builtin_amdgcn_ds_swizzle(__builtin_bit_cast(int, lmv), 0x0203));
    const float g1s  = __builtin_bit_cast(float, __builtin_amdgcn_ds_swizzle(__builtin_bit_cast(int, gv),  0x0203));
    const float lm1 = (n < 4) ? lm1s : 0.0f;
    const float g1 = (n < 4) ? g1s : 0.0f;

    // ---- phase 1: ke=0 MFMA chains (complete first) ----
    f32x4 a00 = {}, a10 = {};
#pragma unroll
    for (int kt = 0; kt < 8; ++kt) {
      const int co = kt * 32 + quad * 8;
      half8 q0 = __builtin_bit_cast(half8, *(const short8*)&bR[n * LDH + co]);
      a00 = __builtin_amdgcn_mfma_f32_16x16x32_f16(__builtin_bit_cast(half8, aU[kt][0]), q0, a00, 0, 0, 0);
      a10 = __builtin_amdgcn_mfma_f32_16x16x32_f16(__builtin_bit_cast(half8, aU[kt][1]), q0, a10, 0, 0, 0);
    }
    // ---- phase 2: ke=1 MFMA chains (independent of ke=0 epilogue) ----
    f32x4 a01 = {}, a11 = {};
#pragma unroll
    for (int kt = 0; kt < 8; ++kt) {
      const int co = kt * 32 + quad * 8;
      short8 b1 = {};
      if (n < 4) b1 = *(const short8*)&bR[(16 + n) * LDH + co];
      half8 q1 = __builtin_bit_cast(half8, b1);
      a01 = __builtin_amdgcn_mfma_f32_16x16x32_f16(__builtin_bit_cast(half8, aU[kt][0]), q1, a01, 0, 0, 0);
      a11 = __builtin_amdgcn_mfma_f32_16x16x32_f16(__builtin_bit_cast(half8, aU[kt][1]), q1, a11, 0, 0, 0);
    }

    // ---- epilogue ke=0 (scheduler hides under phase-2 MFMAs) ----
    float psq0 = 0.0f, pxh0 = 0.0f, psq1 = 0.0f, pxh1 = 0.0f;
    epi_tile(a00, kvReg[0][0], xwEc[0], xEc[0], lm0, g0, hReg[0][0],
             psq0, pxh0, &bW[n * LDH + e0a], true);
    epi_tile(a10, kvReg[1][0], xwEc[1], xEc[1], lm0, g0, hReg[1][0],
             psq0, pxh0, &bW[n * LDH + e0a + 16], true);
    // ---- epilogue ke=1 ----
    epi_tile(a01, kvReg[0][1], xwEc[0], xEc[0], lm1, g1, hReg[0][1],
             psq1, pxh1, &bW[(16 + n) * LDH + e0a], n < 4);
    epi_tile(a11, kvReg[1][1], xwEc[1], xEc[1], lm1, g1, hReg[1][1],
             psq1, pxh1, &bW[(16 + n) * LDH + e0a + 16], n < 4);

    // quad-pair reduce (LDS swizzle) + cross-half on VALU via permlane swap
    psq0 += __shfl_xor(psq0, 16, 64); psq1 += __shfl_xor(psq1, 16, 64);
    pxh0 += __shfl_xor(pxh0, 16, 64); pxh1 += __shfl_xor(pxh1, 16, 64);
    xswap(psq0, psq1); const float sq_s = psq0 + psq1;
    xswap(pxh0, pxh1); const float xh_s = pxh0 + pxh1;
    if (quad == 0) {  // lanes 0..15: totals for k = n
      sRed[wbuf][0][n][w] = sq_s; sRed[wbuf][1][n][w] = xh_s;
    }
    if (quad == 2 && n < 4) {  // lanes 32..35: totals for k = 16+n
      sRed[wbuf][0][16 + n][w] = sq_s; sRed[wbuf][1][16 + n][w] = xh_s;
    }
#pragma unroll
    for (int et = 0; et < 2; ++et) { xEc[et] = xEn[et]; xwEc[et] = xwEn[et]; }
    xkC = xkN;
    __syncthreads();  // the only per-step barrier
  }

  // ---- final lam (per-lane) + emit ----
  const int fb = nAct & 1;
  float lmF0, lmF1 = 0.0f;
  {
    f32x4 qa = *(const f32x4*)&sRed[fb][0][n][0];
    f32x4 qb = *(const f32x4*)&sRed[fb][0][n][4];
    f32x4 qs = qa + qb;
    lmF0 = rsqrtf(fmaxf((qs[0] + qs[1]) + (qs[2] + qs[3]), 1e-12f));
  }
  if (n < 4) {
    f32x4 qa = *(const f32x4*)&sRed[fb][0][16 + n][0];
    f32x4 qb = *(const f32x4*)&sRed[fb][0][16 + n][4];
    f32x4 qs = qa + qb;
    lmF1 = rsqrtf(fmaxf((qs[0] + qs[1]) + (qs[2] + qs[3]), 1e-12f));
  }
#pragma unroll
  for (int et = 0; et < 2; ++et) {
    const int e0 = e0a + 16 * et;
    {
      f32x4 o;
#pragma unroll
      for (int r = 0; r < 4; ++r) o[r] = lmF0 * hReg[et][0][r];
      *(f32x4*)&out[(size_t)(b * K_ + n) * D_ + e0] = o;
    }
    if (n < 4) {
      f32x4 o;
#pragma unroll
      for (int r = 0; r < 4; ++r) o[r] = lmF1 * hReg[et][1][r];
      *(f32x4*)&out[(size_t)(b * K_ + 16 + n) * D_ + e0] = o;
    }
  }
}

extern "C" void kernel_launch(void* const* d_in, const int* in_sizes, int n_in,
                              void* d_out, int out_size, void* d_ws, size_t ws_size,
                              hipStream_t stream) {
  const float* es   = (const float*)d_in[0];
  const int*   mask = (const int*)d_in[1];
  const float* keys = (const float*)d_in[2];
  const float* U    = (const float*)d_in[3];
  const float* V    = (const float*)d_in[4];
  const float* W    = (const float*)d_in[5];
  float* out = (float*)d_out;
  float* XWc = (float*)d_ws;  // compact per-block XW: 256 x 512 x 1KB = 128 MiB
  rnn_fused14<<<B_, NT, 0, stream>>>(es, mask, keys, U, V, W, XWc, out);
}